// Round 1
// baseline (109.688 us; speedup 1.0000x reference)
//
#include <hip/hip_runtime.h>
#include <hip/hip_bf16.h>
#include <hip/hip_cooperative_groups.h>

namespace cg = cooperative_groups;

typedef __attribute__((ext_vector_type(8))) short s16x8;   // 8 bf16 (4 VGPRs)
typedef __attribute__((ext_vector_type(4))) float f32x4;

#define NPTS    8192
#define GSIZE   16384
#define NHL2E   (-0.7213475204444817f)   // -0.5 * log2(e)
#define NSPLIT  32                       // K splits (KCH = 256 each)
#define NBLK    512                      // 4 mt x 4 iyt x 32 s

#define WS_NEEDED ((size_t)NBLK * 3072 * 4)   // 6.3 MB partials

__device__ __forceinline__ unsigned int pk2(float a, float b) {
    // v_cvt_pk_bf16_f32 (RNE) on gfx950: 1 instr for 2 elements
    __hip_bfloat162 h = __float22bfloat162_rn(make_float2(a, b));
    unsigned int u;
    __builtin_memcpy(&u, &h, sizeof(u));   // no-op register alias
    return u;
}

// XOR-swizzled LDS offset (units: shorts). Row stride 512 B == bank 0 mod 32
// for every row, so the unswizzled ds_read_b128 (lanes r=0..15 at the same
// quad offset) was a 16-way bank conflict. Key = (row&7)<<3 shorts (byte bits
// 4..6): reads spread over all 32 banks (2-way residual = free, m136), and
// 16 B alignment is preserved for both the uint2 stores and the b128 reads.
__device__ __forceinline__ int swz(int row, int off) {
    return row * 256 + (off ^ ((row & 7) << 3));
}

// ---- single-dispatch fused: gen(A,B) + MFMA + grid.sync + reduce ----------
// Phase 1: tile = 32m x 32n x 256k per block; partials [b][ch(3)][n][m].
// Phase 2 (blocks 0..255 after grid.sync): split-sum + normalize + store.
__global__ __launch_bounds__(256) void fused_coop_kernel(
    const float* __restrict__ X, const float* __restrict__ Y,
    float* __restrict__ part, float* __restrict__ out)
{
    __shared__ __align__(16) short As[32 * 256];   // 16 KB
    __shared__ __align__(16) short Bs[96 * 256];   // 48 KB  (total 64 KB -> 2 blk/CU)

    const int tid = threadIdx.x;
    const int b   = blockIdx.x;            // 512 blocks
    const int s    = b & (NSPLIT - 1);
    const int rest = b >> 5;
    const int mt = rest & 3, iyt = rest >> 2;

    // --- gen: thread = 8 rows x 4 cols (rg = tid>>6, cb = tid&63) -----------
    const int rg = tid >> 6, cb = tid & 63;
    const float4* X4 = (const float4*)X;   // {x0(k), x1(k), x0(k+1), x1(k+1)}
    const float4* Y4 = (const float4*)Y;
    const int base = s * 128 + cb * 2;     // float4 index (k0 = s*256 + cb*4)
    float4 px0 = X4[base], px1 = X4[base + 1];
    float4 py0 = Y4[base], py1 = Y4[base + 1];
    const float xk[4] = {px0.x, px0.z, px1.x, px1.z};   // X[k,0]
    const float yk[4] = {px0.y, px0.w, px1.y, px1.w};   // X[k,1]
    const float w0[4] = {py0.x, py0.z, py1.x, py1.z};   // Y[k,0]
    const float w1[4] = {py0.y, py0.w, py1.y, py1.w};   // Y[k,1]

    #pragma unroll
    for (int rr = 0; rr < 8; ++rr) {
        const int rm = rg * 8 + rr;        // row 0..31
        float gx = -2.0f + (float)(mt * 32 + rm) * (4.0f / 127.0f);
        float a[4];
        #pragma unroll
        for (int i = 0; i < 4; ++i) {
            float d = gx - xk[i];
            a[i] = __builtin_amdgcn_exp2f(d * d * NHL2E);
        }
        uint2 va;
        va.x = pk2(a[0], a[1]); va.y = pk2(a[2], a[3]);
        *(uint2*)(As + swz(rm, cb * 4)) = va;

        float gy = -2.0f + (float)(iyt * 32 + rm) * (4.0f / 127.0f);
        float e[4];
        #pragma unroll
        for (int i = 0; i < 4; ++i) {
            float d = gy - yk[i];
            e[i] = __builtin_amdgcn_exp2f(d * d * NHL2E);
        }
        uint2 v0, v1, v2;
        v0.x = pk2(e[0], e[1]);             v0.y = pk2(e[2], e[3]);
        v1.x = pk2(e[0]*w0[0], e[1]*w0[1]); v1.y = pk2(e[2]*w0[2], e[3]*w0[3]);
        v2.x = pk2(e[0]*w1[0], e[1]*w1[1]); v2.y = pk2(e[2]*w1[2], e[3]*w1[3]);
        // panel offsets are multiples of 32 rows, so (32k+rm)&7 == rm&7:
        // write key matches the read key (row within panel).
        *(uint2*)(Bs +            swz(rm, cb * 4)) = v0;
        *(uint2*)(Bs + 32 * 256 + swz(rm, cb * 4)) = v1;
        *(uint2*)(Bs + 64 * 256 + swz(rm, cb * 4)) = v2;
    }
    __syncthreads();

    // --- MFMA: wave w -> quadrant (wm, wn); full K=256 ----------------------
    const int w = tid >> 6, lane = tid & 63;
    const int wm = w & 1, wn = w >> 1;
    const int r = lane & 15, quad = lane >> 4;
    const int arow = wm * 16 + r, brow = wn * 16 + r;

    f32x4 a0 = {0.f, 0.f, 0.f, 0.f}, a1 = a0, a2 = a0;
    #pragma unroll
    for (int kk = 0; kk < 256; kk += 32) {
        s16x8 a  = *(const s16x8*)(As +            swz(arow, quad * 8 + kk));
        s16x8 b0 = *(const s16x8*)(Bs +            swz(brow, quad * 8 + kk));
        s16x8 b1 = *(const s16x8*)(Bs + 32 * 256 + swz(brow, quad * 8 + kk));
        s16x8 b2 = *(const s16x8*)(Bs + 64 * 256 + swz(brow, quad * 8 + kk));
        a0 = __builtin_amdgcn_mfma_f32_16x16x32_bf16(a, b0, a0, 0, 0, 0);
        a1 = __builtin_amdgcn_mfma_f32_16x16x32_bf16(a, b1, a1, 0, 0, 0);
        a2 = __builtin_amdgcn_mfma_f32_16x16x32_bf16(a, b2, a2, 0, 0, 0);
    }

    // C/D: col(n)=lane&15, row(m)=quad*4+reg [verified m89/m91]
    float* dst = part + b * 3072;
    const int off = (wn * 16 + r) * 32 + wm * 16 + quad * 4;
    *(f32x4*)(dst + off)        = a0;
    *(f32x4*)(dst + 1024 + off) = a1;
    *(f32x4*)(dst + 2048 + off) = a2;

    cg::this_grid().sync();   // replaces the second dispatch

    // --- phase 2: blocks 0..255, thread = (output, split-quarter) -----------
    if (b < 256) {
        float (*red)[3][64] = (float (*)[3][64])(void*)As;  // alias 3 KB of As
        const int ol = tid & 63, q = tid >> 6;
        const int o = b * 64 + ol;              // o = iy*128 + ix
        const int iy = o >> 7, ix = o & 127;
        const int iyt2 = iy >> 5, nl = iy & 31, mt2 = ix >> 5, ml = ix & 31;
        const float* p = part + (size_t)((iyt2 * 4 + mt2) * 32 + q * 8) * 3072
                         + nl * 32 + ml;
        float f0 = 0.f, f1 = 0.f, f2 = 0.f;
        #pragma unroll
        for (int ss = 0; ss < 8; ++ss) {        // 24 independent loads
            const float* qp = p + ss * 3072;
            f0 += qp[0]; f1 += qp[1024]; f2 += qp[2048];
        }
        red[q][0][ol] = f0; red[q][1][ol] = f1; red[q][2][ol] = f2;
        __syncthreads();
        if (tid < 64) {
            float g0 = red[0][0][tid] + red[1][0][tid] + red[2][0][tid] + red[3][0][tid];
            float g1 = red[0][1][tid] + red[1][1][tid] + red[2][1][tid] + red[3][1][tid];
            float g2 = red[0][2][tid] + red[1][2][tid] + red[2][2][tid] + red[3][2][tid];
            float inv = 1.0f / g0;
            int oo = b * 64 + tid;
            out[oo]          = g0;              // denom: NOT divided
            out[16384 + oo]  = g1 * inv;
            out[32768 + oo]  = g2 * inv;
        }
    }
}

// ---- proven two-kernel path (fallback if cooperative launch fails) ---------
__global__ __launch_bounds__(256) void fused32_kernel(
    const float* __restrict__ X, const float* __restrict__ Y,
    float* __restrict__ part)
{
    __shared__ __align__(16) short As[32 * 256];
    __shared__ __align__(16) short Bs[96 * 256];

    const int tid = threadIdx.x;
    const int b   = blockIdx.x;
    const int s    = b & (NSPLIT - 1);
    const int rest = b >> 5;
    const int mt = rest & 3, iyt = rest >> 2;

    const int rg = tid >> 6, cb = tid & 63;
    const float4* X4 = (const float4*)X;
    const float4* Y4 = (const float4*)Y;
    const int base = s * 128 + cb * 2;
    float4 px0 = X4[base], px1 = X4[base + 1];
    float4 py0 = Y4[base], py1 = Y4[base + 1];
    const float xk[4] = {px0.x, px0.z, px1.x, px1.z};
    const float yk[4] = {px0.y, px0.w, px1.y, px1.w};
    const float w0[4] = {py0.x, py0.z, py1.x, py1.z};
    const float w1[4] = {py0.y, py0.w, py1.y, py1.w};

    #pragma unroll
    for (int rr = 0; rr < 8; ++rr) {
        const int rm = rg * 8 + rr;
        float gx = -2.0f + (float)(mt * 32 + rm) * (4.0f / 127.0f);
        float a[4];
        #pragma unroll
        for (int i = 0; i < 4; ++i) {
            float d = gx - xk[i];
            a[i] = __builtin_amdgcn_exp2f(d * d * NHL2E);
        }
        uint2 va;
        va.x = pk2(a[0], a[1]); va.y = pk2(a[2], a[3]);
        *(uint2*)(As + rm * 256 + cb * 4) = va;

        float gy = -2.0f + (float)(iyt * 32 + rm) * (4.0f / 127.0f);
        float e[4];
        #pragma unroll
        for (int i = 0; i < 4; ++i) {
            float d = gy - yk[i];
            e[i] = __builtin_amdgcn_exp2f(d * d * NHL2E);
        }
        uint2 v0, v1, v2;
        v0.x = pk2(e[0], e[1]);             v0.y = pk2(e[2], e[3]);
        v1.x = pk2(e[0]*w0[0], e[1]*w0[1]); v1.y = pk2(e[2]*w0[2], e[3]*w0[3]);
        v2.x = pk2(e[0]*w1[0], e[1]*w1[1]); v2.y = pk2(e[2]*w1[2], e[3]*w1[3]);
        *(uint2*)(Bs + (rm)      * 256 + cb * 4) = v0;
        *(uint2*)(Bs + (32 + rm) * 256 + cb * 4) = v1;
        *(uint2*)(Bs + (64 + rm) * 256 + cb * 4) = v2;
    }
    __syncthreads();

    const int w = tid >> 6, lane = tid & 63;
    const int wm = w & 1, wn = w >> 1;
    const int r = lane & 15, quad = lane >> 4;
    const short* ap = As + (wm * 16 + r) * 256 + quad * 8;
    const short* bp = Bs + (wn * 16 + r) * 256 + quad * 8;

    f32x4 a0 = {0.f, 0.f, 0.f, 0.f}, a1 = a0, a2 = a0;
    #pragma unroll
    for (int kk = 0; kk < 256; kk += 32) {
        s16x8 a  = *(const s16x8*)(ap + kk);
        s16x8 b0 = *(const s16x8*)(bp + kk);
        s16x8 b1 = *(const s16x8*)(bp + 32 * 256 + kk);
        s16x8 b2 = *(const s16x8*)(bp + 64 * 256 + kk);
        a0 = __builtin_amdgcn_mfma_f32_16x16x32_bf16(a, b0, a0, 0, 0, 0);
        a1 = __builtin_amdgcn_mfma_f32_16x16x32_bf16(a, b1, a1, 0, 0, 0);
        a2 = __builtin_amdgcn_mfma_f32_16x16x32_bf16(a, b2, a2, 0, 0, 0);
    }

    float* dst = part + b * 3072;
    const int off = (wn * 16 + r) * 32 + wm * 16 + quad * 4;
    *(f32x4*)(dst + off)        = a0;
    *(f32x4*)(dst + 1024 + off) = a1;
    *(f32x4*)(dst + 2048 + off) = a2;
}

__global__ __launch_bounds__(256) void reduce32_kernel(
    const float* __restrict__ part, float* __restrict__ out)
{
    __shared__ float red[4][3][64];
    const int tid = threadIdx.x;
    const int ol = tid & 63, q = tid >> 6;
    const int o = blockIdx.x * 64 + ol;
    const int iy = o >> 7, ix = o & 127;
    const int iyt = iy >> 5, nl = iy & 31, mt = ix >> 5, ml = ix & 31;
    const float* p = part + (size_t)((iyt * 4 + mt) * 32 + q * 8) * 3072
                     + nl * 32 + ml;
    float f0 = 0.f, f1 = 0.f, f2 = 0.f;
    #pragma unroll
    for (int s = 0; s < 8; ++s) {
        const float* qp = p + s * 3072;
        f0 += qp[0]; f1 += qp[1024]; f2 += qp[2048];
    }
    red[q][0][ol] = f0; red[q][1][ol] = f1; red[q][2][ol] = f2;
    __syncthreads();
    if (tid < 64) {
        float g0 = red[0][0][tid] + red[1][0][tid] + red[2][0][tid] + red[3][0][tid];
        float g1 = red[0][1][tid] + red[1][1][tid] + red[2][1][tid] + red[3][1][tid];
        float g2 = red[0][2][tid] + red[1][2][tid] + red[2][2][tid] + red[3][2][tid];
        float inv = 1.0f / g0;
        int oo = blockIdx.x * 64 + tid;
        out[oo]          = g0;
        out[16384 + oo]  = g1 * inv;
        out[32768 + oo]  = g2 * inv;
    }
}

// ---- Fallback: proven R1 single-kernel (if ws too small) -------------------
#define TS 1024
__global__ __launch_bounds__(256, 4) void convcnp_fallback(
    const float* __restrict__ X, const float* __restrict__ Y, float* __restrict__ out)
{
    __shared__ float4 tile[TS];
    const int tid = threadIdx.x;
    const int gq  = tid >> 4;
    const int sg  = tid & 15;
    const int gi = blockIdx.x * 16 + gq;
    const int ix = gi >> 7, iy = gi & 127;
    const float gx = -2.0f + (float)ix * (4.0f / 127.0f);
    const float gy = -2.0f + (float)iy * (4.0f / 127.0f);
    float s0 = 0.f, s1 = 0.f, s2 = 0.f;
    const float4* X4 = (const float4*)X;
    const float4* Y4 = (const float4*)Y;
    for (int t = 0; t < NPTS / TS; ++t) {
        #pragma unroll
        for (int i = 0; i < TS / 2; i += 256) {
            float4 xa = X4[t * (TS / 2) + i + tid];
            float4 ya = Y4[t * (TS / 2) + i + tid];
            int p = 2 * (i + tid);
            tile[p]     = make_float4(xa.x, xa.y, ya.x, ya.y);
            tile[p + 1] = make_float4(xa.z, xa.w, ya.z, ya.w);
        }
        __syncthreads();
        #pragma unroll 8
        for (int j = 0; j < TS / 16; ++j) {
            float4 p = tile[j * 16 + sg];
            float dx = gx - p.x, dy = gy - p.y;
            float k = __expf(-0.5f * (dx * dx + dy * dy));
            s0 += k; s1 += k * p.z; s2 += k * p.w;
        }
        __syncthreads();
    }
    #pragma unroll
    for (int off = 8; off >= 1; off >>= 1) {
        s0 += __shfl_down(s0, off, 16);
        s1 += __shfl_down(s1, off, 16);
        s2 += __shfl_down(s2, off, 16);
    }
    if (sg == 0) {
        const int o = iy * 128 + ix;
        float inv = 1.0f / s0;
        out[o] = s0; out[GSIZE + o] = s1 * inv; out[2 * GSIZE + o] = s2 * inv;
    }
}

extern "C" void kernel_launch(void* const* d_in, const int* in_sizes, int n_in,
                              void* d_out, int out_size, void* d_ws, size_t ws_size,
                              hipStream_t stream) {
    const float* X = (const float*)d_in[0];
    const float* Y = (const float*)d_in[1];
    float* out = (float*)d_out;
    if (ws_size >= WS_NEEDED) {
        float* part = (float*)d_ws;
        void* args[] = {(void*)&X, (void*)&Y, (void*)&part, (void*)&out};
        hipError_t err = hipLaunchCooperativeKernel(
            reinterpret_cast<void*>(fused_coop_kernel), dim3(NBLK), dim3(256),
            args, 0, stream);
        if (err != hipSuccess) {
            // cooperative launch unavailable -> proven two-kernel path
            fused32_kernel<<<NBLK, 256, 0, stream>>>(X, Y, part);
            reduce32_kernel<<<GSIZE / 64, 256, 0, stream>>>(part, out);
        }
    } else {
        convcnp_fallback<<<GSIZE / 16, 256, 0, stream>>>(X, Y, out);
    }
}

// Round 2
// 73.306 us; speedup vs baseline: 1.4963x; 1.4963x over previous
//
#include <hip/hip_runtime.h>
#include <hip/hip_bf16.h>

typedef __attribute__((ext_vector_type(8))) short s16x8;   // 8 bf16 (4 VGPRs)
typedef __attribute__((ext_vector_type(4))) float f32x4;

#define GSIZE  16384
#define NHL2E  (-0.7213475204444817f)   // -0.5 * log2(e)

__device__ __forceinline__ unsigned int pk2(float a, float b) {
    // v_cvt_pk_bf16_f32 (RNE) on gfx950: 1 instr for 2 elements
    __hip_bfloat162 h = __float22bfloat162_rn(make_float2(a, b));
    unsigned int u;
    __builtin_memcpy(&u, &h, sizeof(u));   // no-op register alias
    return u;
}

// 8-row x 1024-short panel, XOR-swizzled. Row stride = 2048 B == bank 0 mod
// 128 B, so unswizzled b128 reads (8 rows at same k-offset) would collide;
// key = (row&7)<<3 shorts (byte bits 4..6) spreads rows across all 32 banks
// while preserving 8/16 B alignment for both uint2 stores and b128 reads.
__device__ __forceinline__ int swzC(int row, int off) {
    return row * 1024 + (off ^ ((row & 7) << 3));
}

// ---- single kernel, NO workspace: block = 8x(x) * 8y output tile, K=8192 --
// Per 1024-k chunk: waves 0-3 gen A (8 x-rows), waves 4-7 gen B (8 y-rows x
// 3 ch) -> barrier -> every wave MFMAs its own 128-k window with B packed
// [ch0|ch1] in one fragment (2 MFMAs/k-step), A rows duplicated 0..7 -> 8..15
// (dup C rows ignored). Accumulators live in VGPRs across all 8 chunks; final
// cross-wave reduce in LDS, normalize by ch0 (= denom, weight-1 column).
__global__ __launch_bounds__(512) void convcnp_onek(
    const float* __restrict__ X, const float* __restrict__ Y,
    float* __restrict__ out)
{
    __shared__ __align__(16) short As[8 * 1024];       // 16 KB; aliased as red[]
    __shared__ __align__(16) short Bs[3 * 8 * 1024];   // 48 KB (total 64 KB)

    const int tid = threadIdx.x;
    const int b   = blockIdx.x;          // 256 blocks = 16 xt * 16 yt
    const int xt  = b & 15, yt = b >> 4;

    const int g    = tid & 255;          // k-group (4 k) within chunk
    const int h    = tid >> 8;           // 0: gen A (waves 0-3), 1: gen B (4-7)
    const int wv   = tid >> 6, lane = tid & 63;
    const int r16  = lane & 15, quad = lane >> 4;
    const int row8 = lane & 7;

    const float4* X4 = (const float4*)X;   // {x0(k), x1(k), x0(k+1), x1(k+1)}
    const float4* Y4 = (const float4*)Y;

    f32x4 acc1 = {0.f, 0.f, 0.f, 0.f};    // C[m][n]: n<8 -> ch0, n>=8 -> ch1
    f32x4 acc2 = {0.f, 0.f, 0.f, 0.f};    // ch2 (both halves duplicated)

    for (int c = 0; c < 8; ++c) {
        const int base = c * 512 + g * 2;     // float4 index: k0 = c*1024 + g*4
        if (h == 0) {
            // ---- A panel: A[rr][k] = exp(-.5*(gx(rr) - X[k,0])^2) ----------
            float4 px0 = X4[base], px1 = X4[base + 1];
            const float xk[4] = {px0.x, px0.z, px1.x, px1.z};
            #pragma unroll
            for (int rr = 0; rr < 8; ++rr) {
                float gx = -2.0f + (float)(xt * 8 + rr) * (4.0f / 127.0f);
                float a[4];
                #pragma unroll
                for (int i = 0; i < 4; ++i) {
                    float d = gx - xk[i];
                    a[i] = __builtin_amdgcn_exp2f(d * d * NHL2E);
                }
                uint2 va;
                va.x = pk2(a[0], a[1]); va.y = pk2(a[2], a[3]);
                *(uint2*)(As + swzC(rr, g * 4)) = va;
            }
        } else {
            // ---- B panels: e = exp(-.5*(gy - X[k,1])^2) * {1, Y0, Y1} ------
            float4 px0 = X4[base], px1 = X4[base + 1];
            float4 py0 = Y4[base], py1 = Y4[base + 1];
            const float yk[4] = {px0.y, px0.w, px1.y, px1.w};
            const float w0[4] = {py0.x, py0.z, py1.x, py1.z};
            const float w1[4] = {py0.y, py0.w, py1.y, py1.w};
            #pragma unroll
            for (int rr = 0; rr < 8; ++rr) {
                float gy = -2.0f + (float)(yt * 8 + rr) * (4.0f / 127.0f);
                float e[4];
                #pragma unroll
                for (int i = 0; i < 4; ++i) {
                    float d = gy - yk[i];
                    e[i] = __builtin_amdgcn_exp2f(d * d * NHL2E);
                }
                uint2 v0, v1, v2;
                v0.x = pk2(e[0], e[1]);             v0.y = pk2(e[2], e[3]);
                v1.x = pk2(e[0]*w0[0], e[1]*w0[1]); v1.y = pk2(e[2]*w0[2], e[3]*w0[3]);
                v2.x = pk2(e[0]*w1[0], e[1]*w1[1]); v2.y = pk2(e[2]*w1[2], e[3]*w1[3]);
                *(uint2*)(Bs +         swzC(rr, g * 4)) = v0;
                *(uint2*)(Bs +  8192 + swzC(rr, g * 4)) = v1;
                *(uint2*)(Bs + 16384 + swzC(rr, g * 4)) = v2;
            }
        }
        __syncthreads();

        // ---- MFMA: wave wv owns k-window [wv*128, wv*128+128) --------------
        #pragma unroll
        for (int kk = 0; kk < 128; kk += 32) {
            const int off = wv * 128 + kk + quad * 8;
            // A rows duplicated (lane&7): C rows 8..15 = dup of 0..7, ignored
            s16x8 af = *(const s16x8*)(As + swzC(row8, off));
            // B fragment row r16: r16<8 -> ch0 row r16, r16>=8 -> ch1 row r16-8
            s16x8 b0 = *(const s16x8*)(Bs + (r16 >> 3) * 8192 + swzC(row8, off));
            s16x8 b1 = *(const s16x8*)(Bs + 16384             + swzC(row8, off));
            acc1 = __builtin_amdgcn_mfma_f32_16x16x32_bf16(af, b0, acc1, 0, 0, 0);
            acc2 = __builtin_amdgcn_mfma_f32_16x16x32_bf16(af, b1, acc2, 0, 0, 0);
        }
        __syncthreads();   // protect As/Bs for next chunk's gen
    }

    // ---- cross-wave reduce: red[w][c2][m(16)][n(16)] aliases As (16 KB) ----
    // C/D layout: col(n)=lane&15, row(m)=quad*4+reg [verified m89/m91]
    float* red = (float*)As;
    #pragma unroll
    for (int j = 0; j < 4; ++j) {
        const int m = quad * 4 + j;
        red[wv * 512 +       m * 16 + r16] = acc1[j];
        red[wv * 512 + 256 + m * 16 + r16] = acc2[j];
    }
    __syncthreads();

    if (tid < 64) {
        const int m = tid & 7, y = tid >> 3;    // consecutive tid -> consecutive ix
        float g0 = 0.f, g1 = 0.f, g2 = 0.f;
        #pragma unroll
        for (int w = 0; w < 8; ++w) {
            g0 += red[w * 512 +       m * 16 + y];       // ch0 (denom)
            g1 += red[w * 512 +       m * 16 + 8 + y];   // ch1
            g2 += red[w * 512 + 256 + m * 16 + y];       // ch2
        }
        const int ix = xt * 8 + m, iy = yt * 8 + y;
        const int o = iy * 128 + ix;
        const float inv = 1.0f / g0;
        out[o]             = g0;            // denom: NOT divided
        out[GSIZE + o]     = g1 * inv;
        out[2 * GSIZE + o] = g2 * inv;
    }
}

extern "C" void kernel_launch(void* const* d_in, const int* in_sizes, int n_in,
                              void* d_out, int out_size, void* d_ws, size_t ws_size,
                              hipStream_t stream) {
    const float* X = (const float*)d_in[0];
    const float* Y = (const float*)d_in[1];
    float* out = (float*)d_out;
    (void)d_ws; (void)ws_size;   // deliberately workspace-free (poison probe)
    convcnp_onek<<<256, 512, 0, stream>>>(X, Y, out);
}

// Round 3
// 61.282 us; speedup vs baseline: 1.7899x; 1.1962x over previous
//
#include <hip/hip_runtime.h>
#include <hip/hip_bf16.h>

typedef __attribute__((ext_vector_type(8))) short s16x8;   // 8 bf16 (4 VGPRs)
typedef __attribute__((ext_vector_type(4))) float f32x4;

#define NPTS    8192
#define GSIZE   16384
#define NHL2E   (-0.7213475204444817f)   // -0.5 * log2(e)
#define NSPLIT  32                       // K splits (KCH = 256 each)
#define NBLK    512                      // 4 mt x 4 iyt x 32 s

#define WS_NEEDED ((size_t)NBLK * 3072 * 4)   // 6.3 MB partials

__device__ __forceinline__ unsigned int pk2(float a, float b) {
    // v_cvt_pk_bf16_f32 (RNE) on gfx950: 1 instr for 2 elements
    __hip_bfloat162 h = __float22bfloat162_rn(make_float2(a, b));
    unsigned int u;
    __builtin_memcpy(&u, &h, sizeof(u));   // no-op register alias
    return u;
}

// XOR-swizzled LDS offset (units: shorts). Row stride 512 B == bank 0 mod 32
// for every row, so the unswizzled ds_read_b128 (lanes r=0..15 at the same
// quad offset) was a 16-way bank conflict (262K conflict-cycles measured in
// R1's fused dispatch). Key = (row&7)<<3 shorts (byte bits 4..6): reads
// spread across all 32 banks (2-way residual = free, m136); preserves 8/16 B
// alignment for the uint2 stores and b128 reads. Correctness of this exact
// gen+MFMA swizzle verified in R1 (coop kernel passed).
__device__ __forceinline__ int swz(int row, int off) {
    return row * 256 + (off ^ ((row & 7) << 3));
}

// ---- F: fused gen(A,B in LDS) + MFMA; tile = 32m x 32n x 256k per block ----
// A[m][k] = exp(-.5(xs[mt*32+m]-X[k,0])^2); B_c[n][k] = exp(-.5(ys[iyt*32+n]
// -X[k,1])^2) * {1, Y[k,0], Y[k,1]}.  4 waves = 2x2 quadrants of 16x16.
// Partials: block-contiguous [b][ch(3)][n(32)][m(32)] -> coalesced stores.
__global__ __launch_bounds__(256) void fused32_kernel(
    const float* __restrict__ X, const float* __restrict__ Y,
    float* __restrict__ part)
{
    __shared__ __align__(16) short As[32 * 256];   // 16 KB
    __shared__ __align__(16) short Bs[96 * 256];   // 48 KB  (total 64 KB -> 2 blk/CU)

    const int tid = threadIdx.x;
    const int b   = blockIdx.x;            // 512 blocks
    const int s    = b & (NSPLIT - 1);
    const int rest = b >> 5;
    const int mt = rest & 3, iyt = rest >> 2;

    // --- gen: thread = 8 rows x 4 cols (rg = tid>>6, cb = tid&63) -----------
    const int rg = tid >> 6, cb = tid & 63;
    const float4* X4 = (const float4*)X;   // {x0(k), x1(k), x0(k+1), x1(k+1)}
    const float4* Y4 = (const float4*)Y;
    const int base = s * 128 + cb * 2;     // float4 index (k0 = s*256 + cb*4)
    float4 px0 = X4[base], px1 = X4[base + 1];
    float4 py0 = Y4[base], py1 = Y4[base + 1];
    const float xk[4] = {px0.x, px0.z, px1.x, px1.z};   // X[k,0]
    const float yk[4] = {px0.y, px0.w, px1.y, px1.w};   // X[k,1]
    const float w0[4] = {py0.x, py0.z, py1.x, py1.z};   // Y[k,0]
    const float w1[4] = {py0.y, py0.w, py1.y, py1.w};   // Y[k,1]

    #pragma unroll
    for (int rr = 0; rr < 8; ++rr) {
        const int rm = rg * 8 + rr;        // row 0..31
        float gx = -2.0f + (float)(mt * 32 + rm) * (4.0f / 127.0f);
        float a[4];
        #pragma unroll
        for (int i = 0; i < 4; ++i) {
            float d = gx - xk[i];
            a[i] = __builtin_amdgcn_exp2f(d * d * NHL2E);
        }
        uint2 va;
        va.x = pk2(a[0], a[1]); va.y = pk2(a[2], a[3]);
        *(uint2*)(As + swz(rm, cb * 4)) = va;

        float gy = -2.0f + (float)(iyt * 32 + rm) * (4.0f / 127.0f);
        float e[4];
        #pragma unroll
        for (int i = 0; i < 4; ++i) {
            float d = gy - yk[i];
            e[i] = __builtin_amdgcn_exp2f(d * d * NHL2E);
        }
        uint2 v0, v1, v2;
        v0.x = pk2(e[0], e[1]);             v0.y = pk2(e[2], e[3]);
        v1.x = pk2(e[0]*w0[0], e[1]*w0[1]); v1.y = pk2(e[2]*w0[2], e[3]*w0[3]);
        v2.x = pk2(e[0]*w1[0], e[1]*w1[1]); v2.y = pk2(e[2]*w1[2], e[3]*w1[3]);
        // panel offsets are multiples of 32 rows, so panel-local row & 7 == rm&7:
        // write key matches the read key (row within panel).
        *(uint2*)(Bs +            swz(rm, cb * 4)) = v0;
        *(uint2*)(Bs + 32 * 256 + swz(rm, cb * 4)) = v1;
        *(uint2*)(Bs + 64 * 256 + swz(rm, cb * 4)) = v2;
    }
    __syncthreads();

    // --- MFMA: wave w -> quadrant (wm, wn); full K=256 ----------------------
    const int w = tid >> 6, lane = tid & 63;
    const int wm = w & 1, wn = w >> 1;
    const int r = lane & 15, quad = lane >> 4;
    const int arow = wm * 16 + r, brow = wn * 16 + r;

    f32x4 a0 = {0.f, 0.f, 0.f, 0.f}, a1 = a0, a2 = a0;
    #pragma unroll
    for (int kk = 0; kk < 256; kk += 32) {
        s16x8 a  = *(const s16x8*)(As +            swz(arow, quad * 8 + kk));
        s16x8 b0 = *(const s16x8*)(Bs +            swz(brow, quad * 8 + kk));
        s16x8 b1 = *(const s16x8*)(Bs + 32 * 256 + swz(brow, quad * 8 + kk));
        s16x8 b2 = *(const s16x8*)(Bs + 64 * 256 + swz(brow, quad * 8 + kk));
        a0 = __builtin_amdgcn_mfma_f32_16x16x32_bf16(a, b0, a0, 0, 0, 0);
        a1 = __builtin_amdgcn_mfma_f32_16x16x32_bf16(a, b1, a1, 0, 0, 0);
        a2 = __builtin_amdgcn_mfma_f32_16x16x32_bf16(a, b2, a2, 0, 0, 0);
    }

    // C/D: col(n)=lane&15, row(m)=quad*4+reg [verified m89/m91]
    float* dst = part + b * 3072;
    const int off = (wn * 16 + r) * 32 + wm * 16 + quad * 4;
    *(f32x4*)(dst + off)        = a0;
    *(f32x4*)(dst + 1024 + off) = a1;
    *(f32x4*)(dst + 2048 + off) = a2;
}

// ---- R: 256 blocks x 256 thr; thread = (output, split-quarter); LDS combine -
__global__ __launch_bounds__(256) void reduce32_kernel(
    const float* __restrict__ part, float* __restrict__ out)
{
    __shared__ float red[4][3][64];                 // 3 KB
    const int tid = threadIdx.x;
    const int ol = tid & 63, q = tid >> 6;
    const int o = blockIdx.x * 64 + ol;             // o = iy*128 + ix
    const int iy = o >> 7, ix = o & 127;
    const int iyt = iy >> 5, nl = iy & 31, mt = ix >> 5, ml = ix & 31;
    const float* p = part + (size_t)((iyt * 4 + mt) * 32 + q * 8) * 3072
                     + nl * 32 + ml;
    float f0 = 0.f, f1 = 0.f, f2 = 0.f;
    #pragma unroll
    for (int s = 0; s < 8; ++s) {                   // 24 independent loads
        const float* qp = p + s * 3072;
        f0 += qp[0]; f1 += qp[1024]; f2 += qp[2048];
    }
    red[q][0][ol] = f0; red[q][1][ol] = f1; red[q][2][ol] = f2;
    __syncthreads();
    if (tid < 64) {
        float g0 = red[0][0][tid] + red[1][0][tid] + red[2][0][tid] + red[3][0][tid];
        float g1 = red[0][1][tid] + red[1][1][tid] + red[2][1][tid] + red[3][1][tid];
        float g2 = red[0][2][tid] + red[1][2][tid] + red[2][2][tid] + red[3][2][tid];
        float inv = 1.0f / g0;
        int oo = blockIdx.x * 64 + tid;
        out[oo]          = g0;                      // denom: NOT divided
        out[16384 + oo]  = g1 * inv;
        out[32768 + oo]  = g2 * inv;
    }
}

// ---- Fallback: proven R1 single-kernel (if ws too small) -------------------
#define TS 1024
__global__ __launch_bounds__(256, 4) void convcnp_fallback(
    const float* __restrict__ X, const float* __restrict__ Y, float* __restrict__ out)
{
    __shared__ float4 tile[TS];
    const int tid = threadIdx.x;
    const int gq  = tid >> 4;
    const int sg  = tid & 15;
    const int gi = blockIdx.x * 16 + gq;
    const int ix = gi >> 7, iy = gi & 127;
    const float gx = -2.0f + (float)ix * (4.0f / 127.0f);
    const float gy = -2.0f + (float)iy * (4.0f / 127.0f);
    float s0 = 0.f, s1 = 0.f, s2 = 0.f;
    const float4* X4 = (const float4*)X;
    const float4* Y4 = (const float4*)Y;
    for (int t = 0; t < NPTS / TS; ++t) {
        #pragma unroll
        for (int i = 0; i < TS / 2; i += 256) {
            float4 xa = X4[t * (TS / 2) + i + tid];
            float4 ya = Y4[t * (TS / 2) + i + tid];
            int p = 2 * (i + tid);
            tile[p]     = make_float4(xa.x, xa.y, ya.x, ya.y);
            tile[p + 1] = make_float4(xa.z, xa.w, ya.z, ya.w);
        }
        __syncthreads();
        #pragma unroll 8
        for (int j = 0; j < TS / 16; ++j) {
            float4 p = tile[j * 16 + sg];
            float dx = gx - p.x, dy = gy - p.y;
            float k = __expf(-0.5f * (dx * dx + dy * dy));
            s0 += k; s1 += k * p.z; s2 += k * p.w;
        }
        __syncthreads();
    }
    #pragma unroll
    for (int off = 8; off >= 1; off >>= 1) {
        s0 += __shfl_down(s0, off, 16);
        s1 += __shfl_down(s1, off, 16);
        s2 += __shfl_down(s2, off, 16);
    }
    if (sg == 0) {
        const int o = iy * 128 + ix;
        float inv = 1.0f / s0;
        out[o] = s0; out[GSIZE + o] = s1 * inv; out[2 * GSIZE + o] = s2 * inv;
    }
}

extern "C" void kernel_launch(void* const* d_in, const int* in_sizes, int n_in,
                              void* d_out, int out_size, void* d_ws, size_t ws_size,
                              hipStream_t stream) {
    const float* X = (const float*)d_in[0];
    const float* Y = (const float*)d_in[1];
    float* out = (float*)d_out;
    if (ws_size >= WS_NEEDED) {
        float* part = (float*)d_ws;
        fused32_kernel<<<NBLK, 256, 0, stream>>>(X, Y, part);
        reduce32_kernel<<<GSIZE / 64, 256, 0, stream>>>(part, out);
    } else {
        convcnp_fallback<<<GSIZE / 16, 256, 0, stream>>>(X, Y, out);
    }
}